// Round 1
// baseline (467.300 us; speedup 1.0000x reference)
//
#include <hip/hip_runtime.h>
#include <math.h>

#define DD 256

// ---------------------------------------------------------------------------
// Universal-layer p-vector: p[j] = s[0]^2 after 27 circulant-rotation steps.
// State is batch-independent; one block per output unit j (512 = 2 layers).
// ---------------------------------------------------------------------------
__global__ __launch_bounds__(256)
void universal_p_kernel(const float* __restrict__ u1_w,
                        const float* __restrict__ u2_w,
                        float* __restrict__ p_out /* [512]: p1 then p2 */) {
    __shared__ float s[DD];
    const int j = blockIdx.x & 255;
    const float* uw = (blockIdx.x < 256) ? u1_w : u2_w;
    const int i = threadIdx.x;
    s[i] = 0.0625f;  // 1/sqrt(256)
    __syncthreads();
    for (int t = 0; t < 27; ++t) {
        const int d = t / 3;
        const int g = t - 3 * d;
        const float ang = uw[d * DD * DD + j * DD + g];
        float sn, c;
        sincosf(ang, &sn, &c);
        const float left  = s[(i + DD - 1) & (DD - 1)];
        const float right = s[(i + 1) & (DD - 1)];
        const float mine  = s[i];
        __syncthreads();
        s[i] = c * mine + sn * (left - right);
        __syncthreads();
    }
    if (i == 0) p_out[blockIdx.x] = s[0] * s[0];
}

// ---------------------------------------------------------------------------
// Fused GEMM + epilogue.  C[m,n] over M x 256, K = 256.
//   TRANSB=true : B[k][n] = W[n*256+k]   (h @ W.T, relu layers)
//   TRANSB=false: B[k][n] = W[k*256+n]   (h @ cw, classical part)
//   MODE 0: relu(acc + bias)      MODE 1: tanh(acc + bias + p)
// Block tile 128x64, BK=16, 256 threads, 8x4 per-thread micro-tile.
// ---------------------------------------------------------------------------
template <bool TRANSB, int MODE>
__global__ __launch_bounds__(256)
void gemm_fused(const float* __restrict__ A,
                const float* __restrict__ W,
                const float* __restrict__ bias,
                const float* __restrict__ p,
                float* __restrict__ C,
                int M) {
    __shared__ float As[16][128];  // [k][m]
    __shared__ float Bs[16][64];   // [k][n]

    const int tid = threadIdx.x;
    const int m0 = blockIdx.x * 128;
    const int n0 = blockIdx.y * 64;

    const int tm = tid >> 4;   // 0..15 -> rows tm*8 .. +7
    const int tn = tid & 15;   // 0..15 -> cols tn*4 .. +3

    // loader mappings
    const int lm  = tid >> 2;         // 0..63
    const int lk  = (tid & 3) << 2;   // 0,4,8,12
    const int bk  = tid >> 4;         // 0..15   (!TRANSB)
    const int bnc = (tid & 15) << 2;  // 0..60   (!TRANSB)

    float acc[8][4];
#pragma unroll
    for (int i = 0; i < 8; ++i)
#pragma unroll
        for (int j = 0; j < 4; ++j) acc[i][j] = 0.0f;

    for (int k0 = 0; k0 < 256; k0 += 16) {
        const float4 a0 = *(const float4*)&A[(size_t)(m0 + lm) * 256 + k0 + lk];
        const float4 a1 = *(const float4*)&A[(size_t)(m0 + lm + 64) * 256 + k0 + lk];
        float4 b;
        if (TRANSB) {
            b = *(const float4*)&W[(size_t)(n0 + lm) * 256 + k0 + lk];
        } else {
            b = *(const float4*)&W[(size_t)(k0 + bk) * 256 + n0 + bnc];
        }
        __syncthreads();
        As[lk + 0][lm] = a0.x; As[lk + 1][lm] = a0.y;
        As[lk + 2][lm] = a0.z; As[lk + 3][lm] = a0.w;
        As[lk + 0][lm + 64] = a1.x; As[lk + 1][lm + 64] = a1.y;
        As[lk + 2][lm + 64] = a1.z; As[lk + 3][lm + 64] = a1.w;
        if (TRANSB) {
            Bs[lk + 0][lm] = b.x; Bs[lk + 1][lm] = b.y;
            Bs[lk + 2][lm] = b.z; Bs[lk + 3][lm] = b.w;
        } else {
            *(float4*)&Bs[bk][bnc] = b;
        }
        __syncthreads();

#pragma unroll
        for (int kk = 0; kk < 16; ++kk) {
            float av[8], bv[4];
            *(float4*)&av[0] = *(const float4*)&As[kk][tm * 8];
            *(float4*)&av[4] = *(const float4*)&As[kk][tm * 8 + 4];
            *(float4*)&bv[0] = *(const float4*)&Bs[kk][tn * 4];
#pragma unroll
            for (int i = 0; i < 8; ++i)
#pragma unroll
                for (int j = 0; j < 4; ++j)
                    acc[i][j] = fmaf(av[i], bv[j], acc[i][j]);
        }
    }

    // epilogue
    const float4 bv = *(const float4*)&bias[n0 + tn * 4];
    float4 pv = make_float4(0.f, 0.f, 0.f, 0.f);
    if (MODE == 1) pv = *(const float4*)&p[n0 + tn * 4];

#pragma unroll
    for (int i = 0; i < 8; ++i) {
        float4 v;
        v.x = acc[i][0] + bv.x + pv.x;
        v.y = acc[i][1] + bv.y + pv.y;
        v.z = acc[i][2] + bv.z + pv.z;
        v.w = acc[i][3] + bv.w + pv.w;
        if (MODE == 0) {
            v.x = fmaxf(v.x, 0.f); v.y = fmaxf(v.y, 0.f);
            v.z = fmaxf(v.z, 0.f); v.w = fmaxf(v.w, 0.f);
        } else {
            v.x = tanhf(v.x); v.y = tanhf(v.y);
            v.z = tanhf(v.z); v.w = tanhf(v.w);
        }
        *(float4*)&C[(size_t)(m0 + tm * 8 + i) * 256 + n0 + tn * 4] = v;
    }
}

// ---------------------------------------------------------------------------
extern "C" void kernel_launch(void* const* d_in, const int* in_sizes, int n_in,
                              void* d_out, int out_size, void* d_ws, size_t ws_size,
                              hipStream_t stream) {
    const float* x      = (const float*)d_in[0];
    const float* lin0_w = (const float*)d_in[1];
    const float* lin0_b = (const float*)d_in[2];
    const float* lin1_w = (const float*)d_in[3];
    const float* lin1_b = (const float*)d_in[4];
    const float* u1_w   = (const float*)d_in[5];
    const float* u1_cw  = (const float*)d_in[6];
    const float* u1_cb  = (const float*)d_in[7];
    const float* lin2_w = (const float*)d_in[8];
    const float* lin2_b = (const float*)d_in[9];
    const float* u2_w   = (const float*)d_in[10];
    const float* u2_cw  = (const float*)d_in[11];
    const float* u2_cb  = (const float*)d_in[12];
    const float* lino_w = (const float*)d_in[13];
    const float* lino_b = (const float*)d_in[14];

    float* out  = (float*)d_out;
    float* ws0  = (float*)d_ws;                    // 32768*256 floats (32 MB)
    float* pbuf = ws0 + (size_t)32768 * 256;       // 512 floats: p1, p2

    const int M = 32768;
    dim3 grid(M / 128, DD / 64);
    dim3 block(256);

    // batch-independent universal-layer power terms
    universal_p_kernel<<<dim3(512), block, 0, stream>>>(u1_w, u2_w, pbuf);

    // h1 = relu(x @ W0.T + b0)
    gemm_fused<true, 0><<<grid, block, 0, stream>>>(x, lin0_w, lin0_b, nullptr, ws0, M);
    // h2 = relu(h1 @ W1.T + b1)
    gemm_fused<true, 0><<<grid, block, 0, stream>>>(ws0, lin1_w, lin1_b, nullptr, out, M);
    // h3 = tanh(h2 @ cw1 + cb1 + p1)
    gemm_fused<false, 1><<<grid, block, 0, stream>>>(out, u1_cw, u1_cb, pbuf, ws0, M);
    // h4 = relu(h3 @ W2.T + b2)
    gemm_fused<true, 0><<<grid, block, 0, stream>>>(ws0, lin2_w, lin2_b, nullptr, out, M);
    // h5 = tanh(h4 @ cw2 + cb2 + p2)
    gemm_fused<false, 1><<<grid, block, 0, stream>>>(out, u2_cw, u2_cb, pbuf + 256, ws0, M);
    // out = relu(h5 @ Wo.T + bo)
    gemm_fused<true, 0><<<grid, block, 0, stream>>>(ws0, lino_w, lino_b, nullptr, out, M);
}

// Round 2
// 187.696 us; speedup vs baseline: 2.4897x; 2.4897x over previous
//
#include <hip/hip_runtime.h>
#include <math.h>

#define DD 256

typedef float  f32x4  __attribute__((ext_vector_type(4)));
typedef short  bf16x8 __attribute__((ext_vector_type(8)));

__device__ __forceinline__ unsigned short f2bf(float f) {
    unsigned int u = __float_as_uint(f);
    u = (u + 0x7fffu + ((u >> 16) & 1u)) >> 16;  // RNE
    return (unsigned short)u;
}

// ---------------------------------------------------------------------------
// Universal-layer p-vector: p[j] = s[0]^2 after 27 circulant-rotation steps.
// Batch-independent; one block per output unit j (512 = 2 layers).
// ---------------------------------------------------------------------------
__global__ __launch_bounds__(256)
void universal_p_kernel(const float* __restrict__ u1_w,
                        const float* __restrict__ u2_w,
                        float* __restrict__ p_out /* [512]: p1 then p2 */) {
    __shared__ float s[DD];
    const int j = blockIdx.x & 255;
    const float* uw = (blockIdx.x < 256) ? u1_w : u2_w;
    const int i = threadIdx.x;
    s[i] = 0.0625f;  // 1/sqrt(256)
    __syncthreads();
    for (int t = 0; t < 27; ++t) {
        const int d = t / 3;
        const int g = t - 3 * d;
        const float ang = uw[d * DD * DD + j * DD + g];
        float sn, c;
        sincosf(ang, &sn, &c);
        const float left  = s[(i + DD - 1) & (DD - 1)];
        const float right = s[(i + 1) & (DD - 1)];
        const float mine  = s[i];
        __syncthreads();
        s[i] = c * mine + sn * (left - right);
        __syncthreads();
    }
    if (i == 0) p_out[blockIdx.x] = s[0] * s[0];
}

// ---------------------------------------------------------------------------
// Weight prep: fp32 -> bf16, all matrices laid out [n][k] (B^T form).
// cw matrices (h @ cw) get transposed so every layer is identical.
// grid (256, 6), block 256. mat order: lin0, lin1, cw1^T, lin2, cw2^T, lino.
// ---------------------------------------------------------------------------
__global__ __launch_bounds__(256)
void prep_weights(const float* __restrict__ w0, const float* __restrict__ w1,
                  const float* __restrict__ cw1, const float* __restrict__ w2,
                  const float* __restrict__ cw2, const float* __restrict__ wo,
                  unsigned short* __restrict__ wall) {
    const int mat = blockIdx.y;
    const int n = blockIdx.x;
    const int k = threadIdx.x;
    const float* src;
    bool tr = false;
    switch (mat) {
        case 0: src = w0; break;
        case 1: src = w1; break;
        case 2: src = cw1; tr = true; break;
        case 3: src = w2; break;
        case 4: src = cw2; tr = true; break;
        default: src = wo; break;
    }
    const float v = tr ? src[k * DD + n] : src[n * DD + k];
    wall[mat * 65536 + n * DD + k] = f2bf(v);
}

// ---------------------------------------------------------------------------
// Fused 6-layer network. One block = 64 batch rows through all layers.
// Activations ping-pong between two 64x256 bf16 LDS buffers.
// Each wave: 64x64 output chunk = 4x4 tiles of mfma_f32_16x16x32_bf16.
// ---------------------------------------------------------------------------
template <int MODE, bool LAST>  // MODE 0: relu, 1: tanh(+p)
__device__ __forceinline__ void layer_step(const unsigned short* hc,
                                           unsigned short* hn,
                                           const unsigned short* __restrict__ W,
                                           const float* __restrict__ bias,
                                           const float* __restrict__ pv,
                                           float* __restrict__ out, int m0) {
    const int tid  = threadIdx.x;
    const int wave = tid >> 6;
    const int lane = tid & 63;
    const int quad = lane >> 4;
    const int l15  = lane & 15;
    const int nb   = wave * 64;

    f32x4 acc[4][4];
#pragma unroll
    for (int mi = 0; mi < 4; ++mi)
#pragma unroll
        for (int ni = 0; ni < 4; ++ni) acc[mi][ni] = (f32x4){0.f, 0.f, 0.f, 0.f};

    bf16x8 a_f[2][4], b_f[2][4];
    // preload k0 = 0
    {
        const int kb = quad * 8;
#pragma unroll
        for (int mi = 0; mi < 4; ++mi)
            a_f[0][mi] = *(const bf16x8*)&hc[(mi * 16 + l15) * DD + kb];
#pragma unroll
        for (int ni = 0; ni < 4; ++ni)
            b_f[0][ni] = *(const bf16x8*)&W[(nb + ni * 16 + l15) * DD + kb];
    }
#pragma unroll
    for (int k0 = 0; k0 < 8; ++k0) {
        const int cur = k0 & 1, nxt = cur ^ 1;
        if (k0 < 7) {
            const int kb = (k0 + 1) * 32 + quad * 8;
#pragma unroll
            for (int mi = 0; mi < 4; ++mi)
                a_f[nxt][mi] = *(const bf16x8*)&hc[(mi * 16 + l15) * DD + kb];
#pragma unroll
            for (int ni = 0; ni < 4; ++ni)
                b_f[nxt][ni] = *(const bf16x8*)&W[(nb + ni * 16 + l15) * DD + kb];
        }
#pragma unroll
        for (int mi = 0; mi < 4; ++mi)
#pragma unroll
            for (int ni = 0; ni < 4; ++ni)
                acc[mi][ni] = __builtin_amdgcn_mfma_f32_16x16x32_bf16(
                    a_f[cur][mi], b_f[cur][ni], acc[mi][ni], 0, 0, 0);
    }

    // epilogue: C/D layout col = lane&15, row = quad*4 + reg
#pragma unroll
    for (int ni = 0; ni < 4; ++ni) {
        const int col = nb + ni * 16 + l15;
        float badd = bias[col];
        if (MODE == 1) badd += pv[col];
#pragma unroll
        for (int mi = 0; mi < 4; ++mi) {
            const f32x4 v = acc[mi][ni];
#pragma unroll
            for (int r = 0; r < 4; ++r) {
                float val = v[r] + badd;
                val = (MODE == 1) ? tanhf(val) : fmaxf(val, 0.f);
                const int row = mi * 16 + quad * 4 + r;
                if (LAST)
                    out[(size_t)(m0 + row) * DD + col] = val;
                else
                    hn[row * DD + col] = f2bf(val);
            }
        }
    }
    __syncthreads();
}

__global__ __launch_bounds__(256, 2)
void unet_fused(const float* __restrict__ x,
                const unsigned short* __restrict__ wall,
                const float* __restrict__ b0, const float* __restrict__ b1,
                const float* __restrict__ cb1, const float* __restrict__ b2,
                const float* __restrict__ cb2, const float* __restrict__ bo,
                const float* __restrict__ pbuf,
                float* __restrict__ out) {
    __shared__ __align__(16) unsigned short h[2][64 * DD];
    const int m0 = blockIdx.x * 64;
    const int tid = threadIdx.x;

    // stage x (fp32) -> h[0] (bf16), coalesced: 64 lanes cover one row chunk
    {
        const int c4 = tid & 63;          // float4 column index 0..63
        const int rbase = (tid >> 6) * 16;
#pragma unroll
        for (int i = 0; i < 16; ++i) {
            const int row = rbase + i;
            const float4 v = *(const float4*)&x[(size_t)(m0 + row) * DD + c4 * 4];
            uint2 u;
            u.x = (unsigned int)f2bf(v.x) | ((unsigned int)f2bf(v.y) << 16);
            u.y = (unsigned int)f2bf(v.z) | ((unsigned int)f2bf(v.w) << 16);
            *(uint2*)&h[0][row * DD + c4 * 4] = u;
        }
    }
    __syncthreads();

    layer_step<0, false>(h[0], h[1], wall + 0 * 65536, b0, nullptr, out, m0);
    layer_step<0, false>(h[1], h[0], wall + 1 * 65536, b1, nullptr, out, m0);
    layer_step<1, false>(h[0], h[1], wall + 2 * 65536, cb1, pbuf, out, m0);
    layer_step<0, false>(h[1], h[0], wall + 3 * 65536, b2, nullptr, out, m0);
    layer_step<1, false>(h[0], h[1], wall + 4 * 65536, cb2, pbuf + 256, out, m0);
    layer_step<0, true >(h[1], h[0], wall + 5 * 65536, bo, nullptr, out, m0);
}

// ---------------------------------------------------------------------------
extern "C" void kernel_launch(void* const* d_in, const int* in_sizes, int n_in,
                              void* d_out, int out_size, void* d_ws, size_t ws_size,
                              hipStream_t stream) {
    const float* x      = (const float*)d_in[0];
    const float* lin0_w = (const float*)d_in[1];
    const float* lin0_b = (const float*)d_in[2];
    const float* lin1_w = (const float*)d_in[3];
    const float* lin1_b = (const float*)d_in[4];
    const float* u1_w   = (const float*)d_in[5];
    const float* u1_cw  = (const float*)d_in[6];
    const float* u1_cb  = (const float*)d_in[7];
    const float* lin2_w = (const float*)d_in[8];
    const float* lin2_b = (const float*)d_in[9];
    const float* u2_w   = (const float*)d_in[10];
    const float* u2_cw  = (const float*)d_in[11];
    const float* u2_cb  = (const float*)d_in[12];
    const float* lino_w = (const float*)d_in[13];
    const float* lino_b = (const float*)d_in[14];

    float* out = (float*)d_out;
    unsigned short* wall = (unsigned short*)d_ws;             // 6*65536 bf16 = 768 KB
    float* pbuf = (float*)((char*)d_ws + 6 * 65536 * 2);      // 512 floats

    // batch-independent universal-layer power terms
    universal_p_kernel<<<dim3(512), dim3(256), 0, stream>>>(u1_w, u2_w, pbuf);
    // weights fp32 -> bf16, B^T layout (cw transposed)
    prep_weights<<<dim3(256, 6), dim3(256), 0, stream>>>(
        lin0_w, lin1_w, u1_cw, lin2_w, u2_cw, lino_w, wall);
    // fused 6-layer network: 512 blocks x 64 rows
    unet_fused<<<dim3(512), dim3(256), 0, stream>>>(
        x, wall, lin0_b, lin1_b, u1_cb, lin2_b, u2_cb, lino_b, pbuf, out);
}

// Round 3
// 178.007 us; speedup vs baseline: 2.6252x; 1.0544x over previous
//
#include <hip/hip_runtime.h>
#include <math.h>

#define DD 256

typedef float  f32x4  __attribute__((ext_vector_type(4)));
typedef short  bf16x8 __attribute__((ext_vector_type(8)));

__device__ __forceinline__ unsigned short f2bf(float f) {
    unsigned int u = __float_as_uint(f);
    u = (u + 0x7fffu + ((u >> 16) & 1u)) >> 16;  // RNE
    return (unsigned short)u;
}
__device__ __forceinline__ float bf2f(unsigned int h16) {
    return __uint_as_float(h16 << 16);
}

// ---------------------------------------------------------------------------
// Universal-layer p-vector. The circulant update preserves a uniform state
// exactly (left-right == 0 in fp), so s0 = 0.0625 * prod cos(ang_t) with the
// same fp op order as the simulation (fma(c,s,0) == c*s). p = s0^2.
// grid(2) x 256 threads: blockIdx 0 -> u1, 1 -> u2.
// ---------------------------------------------------------------------------
__global__ __launch_bounds__(256)
void universal_p_kernel(const float* __restrict__ u1_w,
                        const float* __restrict__ u2_w,
                        float* __restrict__ p_out /* [512]: p1 then p2 */) {
    const int j = threadIdx.x;
    const float* uw = blockIdx.x ? u2_w : u1_w;
    float s = 0.0625f;  // 1/sqrt(256)
#pragma unroll
    for (int d = 0; d < 9; ++d)
#pragma unroll
        for (int g = 0; g < 3; ++g)
            s *= cosf(uw[d * DD * DD + j * DD + g]);
    p_out[blockIdx.x * DD + j] = s * s;
}

// ---------------------------------------------------------------------------
// Weight prep: fp32 -> bf16, all matrices laid out [n][k] (B^T form).
// cw matrices (h @ cw) get transposed so every layer is identical.
// ---------------------------------------------------------------------------
__global__ __launch_bounds__(256)
void prep_weights(const float* __restrict__ w0, const float* __restrict__ w1,
                  const float* __restrict__ cw1, const float* __restrict__ w2,
                  const float* __restrict__ cw2, const float* __restrict__ wo,
                  unsigned short* __restrict__ wall) {
    const int mat = blockIdx.y;
    const int n = blockIdx.x;
    const int k = threadIdx.x;
    const float* src;
    bool tr = false;
    switch (mat) {
        case 0: src = w0; break;
        case 1: src = w1; break;
        case 2: src = cw1; tr = true; break;
        case 3: src = w2; break;
        case 4: src = cw2; tr = true; break;
        default: src = wo; break;
    }
    const float v = tr ? src[k * DD + n] : src[n * DD + k];
    wall[mat * 65536 + n * DD + k] = f2bf(v);
}

// ---------------------------------------------------------------------------
// LDS activation layout: 16B chunks. chunk (m, kc) with kc = k/8 lives at
// idx = kc*64 + (m ^ (kc&7)).  Bank = f(m^swz, intra-chunk off) only, so
// MFMA fragment reads (fixed kc per quad, m across lanes) are conflict-free,
// and the swizzle keeps staging (fixed m, kc across lanes) spread too.
// ---------------------------------------------------------------------------
__device__ __forceinline__ int chunk_idx(int m, int kc) {
    return kc * 64 + (m ^ (kc & 7));
}

__device__ __forceinline__ float fast_tanh(float x) {
    const float e = __expf(2.0f * x);                  // v_exp_f32 path
    return 1.0f - 2.0f * __builtin_amdgcn_rcpf(1.0f + e);
}

// ---------------------------------------------------------------------------
// One fused layer. Operands SWAPPED vs naive: A <- W rows (n), B <- h rows
// (m), so D: row(quad*4+r) -> n, col(lane&15) -> m. Each wave owns 64 output
// units (nb = wave*64) for all 64 batch rows: 4x4 tiles of 16x16x32 bf16.
// Epilogue packs 4 consecutive-n bf16 per reg group -> one ds_write_b64.
// ---------------------------------------------------------------------------
template <int MODE>  // 0: relu, 1: tanh(+p)
__device__ __forceinline__ void layer_step(const uint4* hc, uint4* hn,
                                           const unsigned short* __restrict__ W,
                                           const float* __restrict__ bias,
                                           const float* __restrict__ pv) {
    const int tid  = threadIdx.x;
    const int wave = tid >> 6;
    const int lane = tid & 63;
    const int quad = lane >> 4;
    const int l15  = lane & 15;
    const int nb   = wave * 64;

    f32x4 acc[4][4];  // [nt][mt]
#pragma unroll
    for (int nt = 0; nt < 4; ++nt)
#pragma unroll
        for (int mt = 0; mt < 4; ++mt) acc[nt][mt] = (f32x4){0.f, 0.f, 0.f, 0.f};

    bf16x8 w_f[2][4], h_f[2][4];
    {  // preload k0 = 0 (kc = quad)
        const int koff = quad * 8;
#pragma unroll
        for (int nt = 0; nt < 4; ++nt)
            w_f[0][nt] = *(const bf16x8*)&W[(nb + nt * 16 + l15) * DD + koff];
#pragma unroll
        for (int mt = 0; mt < 4; ++mt)
            h_f[0][mt] = *(const bf16x8*)&hc[chunk_idx(mt * 16 + l15, quad)];
    }
#pragma unroll
    for (int k0 = 0; k0 < 8; ++k0) {
        const int cur = k0 & 1, nxt = cur ^ 1;
        if (k0 < 7) {
            const int kc = (k0 + 1) * 4 + quad;
#pragma unroll
            for (int nt = 0; nt < 4; ++nt)
                w_f[nxt][nt] = *(const bf16x8*)&W[(nb + nt * 16 + l15) * DD + kc * 8];
#pragma unroll
            for (int mt = 0; mt < 4; ++mt)
                h_f[nxt][mt] = *(const bf16x8*)&hc[chunk_idx(mt * 16 + l15, kc)];
        }
#pragma unroll
        for (int nt = 0; nt < 4; ++nt)
#pragma unroll
            for (int mt = 0; mt < 4; ++mt)
                acc[nt][mt] = __builtin_amdgcn_mfma_f32_16x16x32_bf16(
                    w_f[cur][nt], h_f[cur][mt], acc[nt][mt], 0, 0, 0);
    }

    // epilogue: thread holds n = n0..n0+3 (consecutive), m = mt*16 + l15
#pragma unroll
    for (int nt = 0; nt < 4; ++nt) {
        const int n0 = nb + nt * 16 + quad * 4;
        f32x4 add = *(const f32x4*)&bias[n0];
        if (MODE == 1) add += *(const f32x4*)&pv[n0];
        const int kc_o = n0 >> 3;
        const int half = quad & 1;
#pragma unroll
        for (int mt = 0; mt < 4; ++mt) {
            const f32x4 v = acc[nt][mt] + add;
            float t0, t1, t2, t3;
            if (MODE == 1) {
                t0 = fast_tanh(v.x); t1 = fast_tanh(v.y);
                t2 = fast_tanh(v.z); t3 = fast_tanh(v.w);
            } else {
                t0 = fmaxf(v.x, 0.f); t1 = fmaxf(v.y, 0.f);
                t2 = fmaxf(v.z, 0.f); t3 = fmaxf(v.w, 0.f);
            }
            uint2 u;
            u.x = (unsigned int)f2bf(t0) | ((unsigned int)f2bf(t1) << 16);
            u.y = (unsigned int)f2bf(t2) | ((unsigned int)f2bf(t3) << 16);
            *(uint2*)((char*)&hn[chunk_idx(mt * 16 + l15, kc_o)] + half * 8) = u;
        }
    }
    __syncthreads();
}

__global__ __launch_bounds__(256, 2)
void unet_fused(const float* __restrict__ x,
                const unsigned short* __restrict__ wall,
                const float* __restrict__ b0, const float* __restrict__ b1,
                const float* __restrict__ cb1, const float* __restrict__ b2,
                const float* __restrict__ cb2, const float* __restrict__ bo,
                const float* __restrict__ pbuf,
                float* __restrict__ out) {
    __shared__ uint4 h[2][2048];  // 2 x 32 KB, chunked+swizzled bf16
    const int m0 = blockIdx.x * 64;
    const int tid = threadIdx.x;
    const int c4 = tid & 63;            // float4 column index (k = c4*4)
    const int rbase = (tid >> 6) * 16;
    const int kc_s = c4 >> 1;
    const int half_s = c4 & 1;

    // stage x (fp32, coalesced) -> h[0] (bf16 chunks)
#pragma unroll
    for (int i = 0; i < 16; ++i) {
        const int row = rbase + i;
        const float4 v = *(const float4*)&x[(size_t)(m0 + row) * DD + c4 * 4];
        uint2 u;
        u.x = (unsigned int)f2bf(v.x) | ((unsigned int)f2bf(v.y) << 16);
        u.y = (unsigned int)f2bf(v.z) | ((unsigned int)f2bf(v.w) << 16);
        *(uint2*)((char*)&h[0][chunk_idx(row, kc_s)] + half_s * 8) = u;
    }
    __syncthreads();

    layer_step<0>(h[0], h[1], wall + 0 * 65536, b0, nullptr);
    layer_step<0>(h[1], h[0], wall + 1 * 65536, b1, nullptr);
    layer_step<1>(h[0], h[1], wall + 2 * 65536, cb1, pbuf);
    layer_step<0>(h[1], h[0], wall + 3 * 65536, b2, nullptr);
    layer_step<1>(h[0], h[1], wall + 4 * 65536, cb2, pbuf + 256);
    layer_step<0>(h[1], h[0], wall + 5 * 65536, bo, nullptr);

    // final activations (bf16) -> fp32, coalesced float4 stores
#pragma unroll
    for (int i = 0; i < 16; ++i) {
        const int row = rbase + i;
        const uint2 u = *(const uint2*)((char*)&h[0][chunk_idx(row, kc_s)] + half_s * 8);
        float4 v;
        v.x = bf2f(u.x & 0xffffu); v.y = bf2f(u.x >> 16);
        v.z = bf2f(u.y & 0xffffu); v.w = bf2f(u.y >> 16);
        *(float4*)&out[(size_t)(m0 + row) * DD + c4 * 4] = v;
    }
}

// ---------------------------------------------------------------------------
extern "C" void kernel_launch(void* const* d_in, const int* in_sizes, int n_in,
                              void* d_out, int out_size, void* d_ws, size_t ws_size,
                              hipStream_t stream) {
    const float* x      = (const float*)d_in[0];
    const float* lin0_w = (const float*)d_in[1];
    const float* lin0_b = (const float*)d_in[2];
    const float* lin1_w = (const float*)d_in[3];
    const float* lin1_b = (const float*)d_in[4];
    const float* u1_w   = (const float*)d_in[5];
    const float* u1_cw  = (const float*)d_in[6];
    const float* u1_cb  = (const float*)d_in[7];
    const float* lin2_w = (const float*)d_in[8];
    const float* lin2_b = (const float*)d_in[9];
    const float* u2_w   = (const float*)d_in[10];
    const float* u2_cw  = (const float*)d_in[11];
    const float* u2_cb  = (const float*)d_in[12];
    const float* lino_w = (const float*)d_in[13];
    const float* lino_b = (const float*)d_in[14];

    float* out = (float*)d_out;
    unsigned short* wall = (unsigned short*)d_ws;         // 6*65536 bf16 = 768 KB
    float* pbuf = (float*)((char*)d_ws + 6 * 65536 * 2);  // 512 floats

    universal_p_kernel<<<dim3(2), dim3(256), 0, stream>>>(u1_w, u2_w, pbuf);
    prep_weights<<<dim3(256, 6), dim3(256), 0, stream>>>(
        lin0_w, lin1_w, u1_cw, lin2_w, u2_cw, lino_w, wall);
    unet_fused<<<dim3(512), dim3(256), 0, stream>>>(
        x, wall, lin0_b, lin1_b, u1_cb, lin2_b, u2_cb, lino_b, pbuf, out);
}